// Round 3
// baseline (524.969 us; speedup 1.0000x reference)
//
#include <hip/hip_runtime.h>
#include <hip/hip_bf16.h>

#define S_LEN 4096
#define EMB   768
#define NH    12
#define DH    64

// finite sentinel instead of -INFINITY: safe under fast-math builds
#define NEG_BIG (-1e30f)

using bf16x8 = __attribute__((ext_vector_type(8))) short;
using f32x4  = __attribute__((ext_vector_type(4))) float;

__device__ __forceinline__ short f2bf(float f) {
    __hip_bfloat16 h = __float2bfloat16(f);
    short s; __builtin_memcpy(&s, &h, 2); return s;
}

// ---------------------------------------------------------------------------
// Kernel 1: QKV projection.  C[m,n] = sum_k X[m,k] * Wqkv[n,k] + b[n]
// X:[4096,768] fp32, W:[2304,768] fp32, Bias:[2304] fp32.
// fp32 -> bf16 conversion happens during LDS staging.
// Epilogue scatters bf16 to Q[h][s][d], K[h][s][d], Vt[h][d][s] in workspace.
// ---------------------------------------------------------------------------
__global__ __launch_bounds__(256) void qkv_gemm(
    const float* __restrict__ X, const float* __restrict__ W,
    const float* __restrict__ Bias,
    short* __restrict__ Qw, short* __restrict__ Kw, short* __restrict__ Vt)
{
    __shared__ __align__(16) short As[128 * 32];
    __shared__ __align__(16) short Bs[128 * 32];

    const int m0 = blockIdx.x * 128;
    const int n0 = blockIdx.y * 128;
    const int t = threadIdx.x;
    const int lane = t & 63, wave = t >> 6;
    const int quad = lane >> 4, l16 = lane & 15;
    const int wm = (wave >> 1) * 64, wn = (wave & 1) * 64;

    f32x4 acc[4][4] = {};

    for (int k0 = 0; k0 < EMB; k0 += 32) {
        __syncthreads();
        // stage A and B tiles: 128x32 fp32 each -> bf16 LDS. 1024 float4 chunks.
        for (int c = t; c < 1024; c += 256) {
            const int row = c >> 3, cc = (c & 7) * 4;
            const float4 va = *(const float4*)&X[(size_t)(m0 + row) * EMB + k0 + cc];
            short4 sa; sa.x = f2bf(va.x); sa.y = f2bf(va.y);
                       sa.z = f2bf(va.z); sa.w = f2bf(va.w);
            *(short4*)&As[row * 32 + cc] = sa;
            const float4 vb = *(const float4*)&W[(size_t)(n0 + row) * EMB + k0 + cc];
            short4 sb; sb.x = f2bf(vb.x); sb.y = f2bf(vb.y);
                       sb.z = f2bf(vb.z); sb.w = f2bf(vb.w);
            *(short4*)&Bs[row * 32 + cc] = sb;
        }
        __syncthreads();

        bf16x8 af[4], bfr[4];
        #pragma unroll
        for (int i = 0; i < 4; i++)
            af[i] = *(const bf16x8*)&As[(wm + i * 16 + l16) * 32 + quad * 8];
        #pragma unroll
        for (int j = 0; j < 4; j++)
            bfr[j] = *(const bf16x8*)&Bs[(wn + j * 16 + l16) * 32 + quad * 8];
        #pragma unroll
        for (int i = 0; i < 4; i++)
            #pragma unroll
            for (int j = 0; j < 4; j++)
                acc[i][j] = __builtin_amdgcn_mfma_f32_16x16x32_bf16(
                    af[i], bfr[j], acc[i][j], 0, 0, 0);
    }

    // C/D layout: col = lane&15, row = quad*4 + reg
    #pragma unroll
    for (int j = 0; j < 4; j++) {
        const int n = n0 + wn + j * 16 + l16;      // global output col (0..2303)
        const float bias = Bias[n];
        const int part = n / EMB;                  // 0=Q 1=K 2=V (block-uniform)
        const int r768 = n % EMB;
        const int h = r768 >> 6, d = r768 & 63;
        #pragma unroll
        for (int i = 0; i < 4; i++) {
            #pragma unroll
            for (int r = 0; r < 4; r++) {
                const int m = m0 + wm + i * 16 + quad * 4 + r;  // seq position
                const short o = f2bf(acc[i][j][r] + bias);
                if (part == 0)
                    Qw[((size_t)h * S_LEN + m) * DH + d] = o;
                else if (part == 1)
                    Kw[((size_t)h * S_LEN + m) * DH + d] = o;
                else
                    Vt[((size_t)h * DH + d) * S_LEN + m] = o;
            }
        }
    }
}

// ---------------------------------------------------------------------------
// Kernel 2: causal flash attention (NO 1/sqrt(dh) scaling, per reference).
// Block = (q-tile of 128, head). 4 waves x 32 q-rows. K/V tiles of 128 in LDS.
// All operands bf16 from workspace.
// ---------------------------------------------------------------------------
__global__ __launch_bounds__(256) void flash_attn(
    const short* __restrict__ Qw, const short* __restrict__ Kw,
    const short* __restrict__ Vt, short* __restrict__ Ctx)
{
    __shared__ __align__(16) short Ks[128 * 64];    // [k][d]   16 KB
    __shared__ __align__(16) short Vs[64 * 128];    // [d][k]   16 KB
    __shared__ __align__(16) short Ps[4][32 * 128]; // per-wave 32 KB

    const int h  = blockIdx.y;
    const int qt = (gridDim.x - 1) - blockIdx.x;   // heavy q-tiles first
    const int q0 = qt * 128;
    const int t = threadIdx.x;
    const int lane = t & 63, wave = t >> 6;
    const int quad = lane >> 4, l16 = lane & 15;
    const int qw0 = q0 + wave * 32;

    // Q fragments in registers: A-layout (m = l16, k = quad*8 + j)
    bf16x8 qf[2][2];
    #pragma unroll
    for (int i = 0; i < 2; i++)
        #pragma unroll
        for (int kb = 0; kb < 2; kb++)
            qf[i][kb] = *(const bf16x8*)
                &Qw[((size_t)h * S_LEN + qw0 + i * 16 + l16) * DH + kb * 32 + quad * 8];

    float m_i[2][4], l_i[2][4];
    f32x4 o_acc[2][4] = {};
    #pragma unroll
    for (int i = 0; i < 2; i++)
        #pragma unroll
        for (int r = 0; r < 4; r++) { m_i[i][r] = NEG_BIG; l_i[i][r] = 0.f; }

    for (int kt = 0; kt <= qt; kt++) {
        const int k0 = kt * 128;
        __syncthreads();
        for (int c = t; c < 1024; c += 256) {
            const int row = c >> 3, cc = (c & 7) * 8;
            *(bf16x8*)&Ks[row * 64 + cc] =
                *(const bf16x8*)&Kw[((size_t)h * S_LEN + k0 + row) * DH + cc];
        }
        for (int c = t; c < 1024; c += 256) {
            const int row = c >> 4, cc = (c & 15) * 8;
            *(bf16x8*)&Vs[row * 128 + cc] =
                *(const bf16x8*)&Vt[((size_t)h * DH + row) * S_LEN + k0 + cc];
        }
        __syncthreads();

        // S = Q K^T
        f32x4 sf[2][8] = {};
        #pragma unroll
        for (int j = 0; j < 8; j++) {
            #pragma unroll
            for (int kb = 0; kb < 2; kb++) {
                const bf16x8 kf = *(const bf16x8*)
                    &Ks[(j * 16 + l16) * 64 + kb * 32 + quad * 8];
                #pragma unroll
                for (int i = 0; i < 2; i++)
                    sf[i][j] = __builtin_amdgcn_mfma_f32_16x16x32_bf16(
                        qf[i][kb], kf, sf[i][j], 0, 0, 0);
            }
        }

        const bool diag = (kt == qt);
        #pragma unroll
        for (int i = 0; i < 2; i++) {
            if (diag) {
                const int qbase = qw0 + i * 16 + quad * 4;  // + r
                const int kbase = k0 + l16;                  // + j*16
                #pragma unroll
                for (int j = 0; j < 8; j++)
                    #pragma unroll
                    for (int r = 0; r < 4; r++)
                        if (kbase + j * 16 > qbase + r) sf[i][j][r] = NEG_BIG;
            }
            #pragma unroll
            for (int r = 0; r < 4; r++) {
                float mx = sf[i][0][r];
                #pragma unroll
                for (int j = 1; j < 8; j++) mx = fmaxf(mx, sf[i][j][r]);
                #pragma unroll
                for (int off = 1; off < 16; off <<= 1)
                    mx = fmaxf(mx, __shfl_xor(mx, off, 64));
                const float mnew = fmaxf(m_i[i][r], mx);
                const float alpha = __expf(m_i[i][r] - mnew);
                m_i[i][r] = mnew;
                float rs = 0.f;
                #pragma unroll
                for (int j = 0; j < 8; j++) {
                    const float p = __expf(sf[i][j][r] - mnew);
                    sf[i][j][r] = p;
                    rs += p;
                }
                #pragma unroll
                for (int off = 1; off < 16; off <<= 1)
                    rs += __shfl_xor(rs, off, 64);
                l_i[i][r] = l_i[i][r] * alpha + rs;
                #pragma unroll
                for (int db = 0; db < 4; db++) o_acc[i][db][r] *= alpha;
            }
            // P (C-layout) -> per-wave LDS row-major [32][128] as bf16
            #pragma unroll
            for (int j = 0; j < 8; j++)
                #pragma unroll
                for (int r = 0; r < 4; r++)
                    Ps[wave][(i * 16 + quad * 4 + r) * 128 + j * 16 + l16] =
                        f2bf(sf[i][j][r]);
        }

        // O += P V
        #pragma unroll
        for (int kb = 0; kb < 4; kb++) {
            bf16x8 pf[2];
            #pragma unroll
            for (int i = 0; i < 2; i++)
                pf[i] = *(const bf16x8*)
                    &Ps[wave][(i * 16 + l16) * 128 + kb * 32 + quad * 8];
            #pragma unroll
            for (int db = 0; db < 4; db++) {
                const bf16x8 vf = *(const bf16x8*)
                    &Vs[(db * 16 + l16) * 128 + kb * 32 + quad * 8];
                #pragma unroll
                for (int i = 0; i < 2; i++)
                    o_acc[i][db] = __builtin_amdgcn_mfma_f32_16x16x32_bf16(
                        pf[i], vf, o_acc[i][db], 0, 0, 0);
            }
        }
    }

    // normalize, write context bf16 [s][h*64+d]
    #pragma unroll
    for (int i = 0; i < 2; i++)
        #pragma unroll
        for (int r = 0; r < 4; r++) {
            const float li = l_i[i][r];
            const float inv = (li > 0.f) ? 1.0f / li : 0.f;
            const int m = qw0 + i * 16 + quad * 4 + r;
            #pragma unroll
            for (int db = 0; db < 4; db++) {
                const int d = db * 16 + l16;
                Ctx[(size_t)m * EMB + h * DH + d] = f2bf(o_acc[i][db][r] * inv);
            }
        }
}

// ---------------------------------------------------------------------------
// Kernel 3: output projection. out[m,n] = sum_k Ctx[m,k] * Wout[n,k] + b[n]
// Ctx bf16 workspace; Wout/Bias fp32; Out fp32.
// ---------------------------------------------------------------------------
__global__ __launch_bounds__(256) void out_gemm(
    const short* __restrict__ A, const float* __restrict__ W,
    const float* __restrict__ Bias, float* __restrict__ Out)
{
    __shared__ __align__(16) short As[128 * 32];
    __shared__ __align__(16) short Bs[128 * 32];

    const int m0 = blockIdx.x * 128;
    const int n0 = blockIdx.y * 128;
    const int t = threadIdx.x;
    const int lane = t & 63, wave = t >> 6;
    const int quad = lane >> 4, l16 = lane & 15;
    const int wm = (wave >> 1) * 64, wn = (wave & 1) * 64;

    f32x4 acc[4][4] = {};

    for (int k0 = 0; k0 < EMB; k0 += 32) {
        __syncthreads();
        // A tile: bf16 source, 512 x 16B chunks
        for (int c = t; c < 512; c += 256) {
            const int row = c >> 2, cc = (c & 3) * 8;
            *(bf16x8*)&As[row * 32 + cc] =
                *(const bf16x8*)&A[(size_t)(m0 + row) * EMB + k0 + cc];
        }
        // B tile: fp32 source -> bf16, 1024 float4 chunks
        for (int c = t; c < 1024; c += 256) {
            const int row = c >> 3, cc = (c & 7) * 4;
            const float4 vb = *(const float4*)&W[(size_t)(n0 + row) * EMB + k0 + cc];
            short4 sb; sb.x = f2bf(vb.x); sb.y = f2bf(vb.y);
                       sb.z = f2bf(vb.z); sb.w = f2bf(vb.w);
            *(short4*)&Bs[row * 32 + cc] = sb;
        }
        __syncthreads();

        bf16x8 af[4], bfr[4];
        #pragma unroll
        for (int i = 0; i < 4; i++)
            af[i] = *(const bf16x8*)&As[(wm + i * 16 + l16) * 32 + quad * 8];
        #pragma unroll
        for (int j = 0; j < 4; j++)
            bfr[j] = *(const bf16x8*)&Bs[(wn + j * 16 + l16) * 32 + quad * 8];
        #pragma unroll
        for (int i = 0; i < 4; i++)
            #pragma unroll
            for (int j = 0; j < 4; j++)
                acc[i][j] = __builtin_amdgcn_mfma_f32_16x16x32_bf16(
                    af[i], bfr[j], acc[i][j], 0, 0, 0);
    }

    #pragma unroll
    for (int j = 0; j < 4; j++) {
        const int n = n0 + wn + j * 16 + l16;
        const float bias = Bias[n];
        #pragma unroll
        for (int i = 0; i < 4; i++)
            #pragma unroll
            for (int r = 0; r < 4; r++) {
                const int m = m0 + wm + i * 16 + quad * 4 + r;
                Out[(size_t)m * EMB + n] = acc[i][j][r] + bias;
            }
    }
}

// ---------------------------------------------------------------------------
extern "C" void kernel_launch(void* const* d_in, const int* in_sizes, int n_in,
                              void* d_out, int out_size, void* d_ws, size_t ws_size,
                              hipStream_t stream)
{
    (void)in_sizes; (void)n_in; (void)out_size; (void)ws_size;
    const float* x     = (const float*)d_in[0];
    // d_in[1] = causal mask, not read (causality computed from indices)
    const float* w_qkv = (const float*)d_in[2];
    const float* b_qkv = (const float*)d_in[3];
    const float* w_out = (const float*)d_in[4];
    const float* b_out = (const float*)d_in[5];
    float* out = (float*)d_out;

    char* ws = (char*)d_ws;
    const size_t SEG = (size_t)NH * S_LEN * DH * sizeof(short);  // 6 MB
    short* Qw  = (short*)(ws);
    short* Kw  = (short*)(ws + SEG);
    short* Vt  = (short*)(ws + 2 * SEG);
    short* Ctx = (short*)(ws + 3 * SEG);

    qkv_gemm <<<dim3(S_LEN / 128, (3 * EMB) / 128), 256, 0, stream>>>(
        x, w_qkv, b_qkv, Qw, Kw, Vt);
    flash_attn<<<dim3(S_LEN / 128, NH), 256, 0, stream>>>(Qw, Kw, Vt, Ctx);
    out_gemm <<<dim3(S_LEN / 128, EMB / 128), 256, 0, stream>>>(
        Ctx, w_out, b_out, out);
}

// Round 4
// 476.745 us; speedup vs baseline: 1.1012x; 1.1012x over previous
//
#include <hip/hip_runtime.h>
#include <hip/hip_bf16.h>

#define S_LEN 4096
#define EMB   768
#define NH    12
#define DH    64
#define NCHUNK 4          // k-chunks of 1024 for split-K flash

// finite sentinel instead of -INFINITY: safe under fast-math builds
#define NEG_BIG (-1e30f)

using bf16x8 = __attribute__((ext_vector_type(8))) short;
using f32x4  = __attribute__((ext_vector_type(4))) float;

__device__ __forceinline__ short f2bf(float f) {
    __hip_bfloat16 h = __float2bfloat16(f);
    short s; __builtin_memcpy(&s, &h, 2); return s;
}
__device__ __forceinline__ float bf2f(short s) {
    __hip_bfloat16 h; __builtin_memcpy(&h, &s, 2);
    return __bfloat162float(h);
}

// ---------------------------------------------------------------------------
// Kernel 1: QKV projection (unchanged from R3, passing).
// ---------------------------------------------------------------------------
__global__ __launch_bounds__(256) void qkv_gemm(
    const float* __restrict__ X, const float* __restrict__ W,
    const float* __restrict__ Bias,
    short* __restrict__ Qw, short* __restrict__ Kw, short* __restrict__ Vt)
{
    __shared__ __align__(16) short As[128 * 32];
    __shared__ __align__(16) short Bs[128 * 32];

    const int m0 = blockIdx.x * 128;
    const int n0 = blockIdx.y * 128;
    const int t = threadIdx.x;
    const int lane = t & 63, wave = t >> 6;
    const int quad = lane >> 4, l16 = lane & 15;
    const int wm = (wave >> 1) * 64, wn = (wave & 1) * 64;

    f32x4 acc[4][4] = {};

    for (int k0 = 0; k0 < EMB; k0 += 32) {
        __syncthreads();
        for (int c = t; c < 1024; c += 256) {
            const int row = c >> 3, cc = (c & 7) * 4;
            const float4 va = *(const float4*)&X[(size_t)(m0 + row) * EMB + k0 + cc];
            short4 sa; sa.x = f2bf(va.x); sa.y = f2bf(va.y);
                       sa.z = f2bf(va.z); sa.w = f2bf(va.w);
            *(short4*)&As[row * 32 + cc] = sa;
            const float4 vb = *(const float4*)&W[(size_t)(n0 + row) * EMB + k0 + cc];
            short4 sb; sb.x = f2bf(vb.x); sb.y = f2bf(vb.y);
                       sb.z = f2bf(vb.z); sb.w = f2bf(vb.w);
            *(short4*)&Bs[row * 32 + cc] = sb;
        }
        __syncthreads();

        bf16x8 af[4], bfr[4];
        #pragma unroll
        for (int i = 0; i < 4; i++)
            af[i] = *(const bf16x8*)&As[(wm + i * 16 + l16) * 32 + quad * 8];
        #pragma unroll
        for (int j = 0; j < 4; j++)
            bfr[j] = *(const bf16x8*)&Bs[(wn + j * 16 + l16) * 32 + quad * 8];
        #pragma unroll
        for (int i = 0; i < 4; i++)
            #pragma unroll
            for (int j = 0; j < 4; j++)
                acc[i][j] = __builtin_amdgcn_mfma_f32_16x16x32_bf16(
                    af[i], bfr[j], acc[i][j], 0, 0, 0);
    }

    #pragma unroll
    for (int j = 0; j < 4; j++) {
        const int n = n0 + wn + j * 16 + l16;
        const float bias = Bias[n];
        const int part = n / EMB;
        const int r768 = n % EMB;
        const int h = r768 >> 6, d = r768 & 63;
        #pragma unroll
        for (int i = 0; i < 4; i++) {
            #pragma unroll
            for (int r = 0; r < 4; r++) {
                const int m = m0 + wm + i * 16 + quad * 4 + r;
                const short o = f2bf(acc[i][j][r] + bias);
                if (part == 0)
                    Qw[((size_t)h * S_LEN + m) * DH + d] = o;
                else if (part == 1)
                    Kw[((size_t)h * S_LEN + m) * DH + d] = o;
                else
                    Vt[((size_t)h * DH + d) * S_LEN + m] = o;
            }
        }
    }
}

// ---------------------------------------------------------------------------
// Kernel 2a: split-K flash partial. Block = (q-tile 128, head, k-chunk 1024).
// Writes unnormalized O and (m,l) per q-row. <= 8 k-iterations per block.
// LDS 48 KB -> 3 blocks/CU.
// ---------------------------------------------------------------------------
__global__ __launch_bounds__(256) void flash_partial(
    const short* __restrict__ Qw, const short* __restrict__ Kw,
    const short* __restrict__ Vt,
    short* __restrict__ Opart, float* __restrict__ Mpart,
    float* __restrict__ Lpart)
{
    const int qt = blockIdx.x;
    const int h  = blockIdx.y;
    const int kc = blockIdx.z;
    const int q0  = qt * 128;
    const int ks0 = kc * 1024;
    if (ks0 > q0) return;                       // chunk entirely masked
    const int nk = min(8, (q0 - ks0) / 128 + 1);

    __shared__ __align__(16) short Ks[128 * 64];    // [k][d]      16 KB
    __shared__ __align__(16) short Vs[64 * 128];    // [d][k]      16 KB
    __shared__ __align__(16) short Ps[4][32 * 64];  // half-width  16 KB

    const int t = threadIdx.x;
    const int lane = t & 63, wave = t >> 6;
    const int quad = lane >> 4, l16 = lane & 15;
    const int qw0 = q0 + wave * 32;

    bf16x8 qf[2][2];
    #pragma unroll
    for (int i = 0; i < 2; i++)
        #pragma unroll
        for (int kb = 0; kb < 2; kb++)
            qf[i][kb] = *(const bf16x8*)
                &Qw[((size_t)h * S_LEN + qw0 + i * 16 + l16) * DH + kb * 32 + quad * 8];

    float m_i[2][4], l_i[2][4];
    f32x4 o_acc[2][4] = {};
    #pragma unroll
    for (int i = 0; i < 2; i++)
        #pragma unroll
        for (int r = 0; r < 4; r++) { m_i[i][r] = NEG_BIG; l_i[i][r] = 0.f; }

    for (int kt = 0; kt < nk; kt++) {
        const int k0 = ks0 + kt * 128;
        __syncthreads();
        for (int c = t; c < 1024; c += 256) {
            const int row = c >> 3, cc = (c & 7) * 8;
            *(bf16x8*)&Ks[row * 64 + cc] =
                *(const bf16x8*)&Kw[((size_t)h * S_LEN + k0 + row) * DH + cc];
        }
        for (int c = t; c < 1024; c += 256) {
            const int row = c >> 4, cc = (c & 15) * 8;
            *(bf16x8*)&Vs[row * 128 + cc] =
                *(const bf16x8*)&Vt[((size_t)h * DH + row) * S_LEN + k0 + cc];
        }
        __syncthreads();

        // S = Q K^T
        f32x4 sf[2][8] = {};
        #pragma unroll
        for (int j = 0; j < 8; j++) {
            #pragma unroll
            for (int kb = 0; kb < 2; kb++) {
                const bf16x8 kf = *(const bf16x8*)
                    &Ks[(j * 16 + l16) * 64 + kb * 32 + quad * 8];
                #pragma unroll
                for (int i = 0; i < 2; i++)
                    sf[i][j] = __builtin_amdgcn_mfma_f32_16x16x32_bf16(
                        qf[i][kb], kf, sf[i][j], 0, 0, 0);
            }
        }

        const bool diag = (k0 == q0);
        #pragma unroll
        for (int i = 0; i < 2; i++) {
            if (diag) {
                const int qbase = qw0 + i * 16 + quad * 4;
                const int kbase = k0 + l16;
                #pragma unroll
                for (int j = 0; j < 8; j++)
                    #pragma unroll
                    for (int r = 0; r < 4; r++)
                        if (kbase + j * 16 > qbase + r) sf[i][j][r] = NEG_BIG;
            }
            #pragma unroll
            for (int r = 0; r < 4; r++) {
                float mx = sf[i][0][r];
                #pragma unroll
                for (int j = 1; j < 8; j++) mx = fmaxf(mx, sf[i][j][r]);
                #pragma unroll
                for (int off = 1; off < 16; off <<= 1)
                    mx = fmaxf(mx, __shfl_xor(mx, off, 64));
                const float mnew = fmaxf(m_i[i][r], mx);
                const float alpha = __expf(m_i[i][r] - mnew);
                m_i[i][r] = mnew;
                float rs = 0.f;
                #pragma unroll
                for (int j = 0; j < 8; j++) {
                    const float p = __expf(sf[i][j][r] - mnew);
                    sf[i][j][r] = p;
                    rs += p;
                }
                #pragma unroll
                for (int off = 1; off < 16; off <<= 1)
                    rs += __shfl_xor(rs, off, 64);
                l_i[i][r] = l_i[i][r] * alpha + rs;
                #pragma unroll
                for (int db = 0; db < 4; db++) o_acc[i][db][r] *= alpha;
            }
        }

        // O += P V, in two k-halves (Ps holds 32x64 per wave)
        #pragma unroll
        for (int half = 0; half < 2; half++) {
            #pragma unroll
            for (int i = 0; i < 2; i++)
                #pragma unroll
                for (int j = 4 * half; j < 4 * half + 4; j++)
                    #pragma unroll
                    for (int r = 0; r < 4; r++)
                        Ps[wave][(i * 16 + quad * 4 + r) * 64
                                 + (j - 4 * half) * 16 + l16] = f2bf(sf[i][j][r]);
            #pragma unroll
            for (int kbl = 0; kbl < 2; kbl++) {
                const int kb = half * 2 + kbl;
                bf16x8 pf[2];
                #pragma unroll
                for (int i = 0; i < 2; i++)
                    pf[i] = *(const bf16x8*)
                        &Ps[wave][(i * 16 + l16) * 64 + kbl * 32 + quad * 8];
                #pragma unroll
                for (int db = 0; db < 4; db++) {
                    const bf16x8 vf = *(const bf16x8*)
                        &Vs[(db * 16 + l16) * 128 + kb * 32 + quad * 8];
                    #pragma unroll
                    for (int i = 0; i < 2; i++)
                        o_acc[i][db] = __builtin_amdgcn_mfma_f32_16x16x32_bf16(
                            pf[i], vf, o_acc[i][db], 0, 0, 0);
                }
            }
        }
    }

    // write partials (unnormalized)
    const size_t slab = ((size_t)h * NCHUNK + kc) * S_LEN;
    #pragma unroll
    for (int i = 0; i < 2; i++)
        #pragma unroll
        for (int r = 0; r < 4; r++) {
            const int q = qw0 + i * 16 + quad * 4 + r;
            if (l16 == 0) {
                Mpart[slab + q] = m_i[i][r];
                Lpart[slab + q] = l_i[i][r];
            }
            #pragma unroll
            for (int db = 0; db < 4; db++) {
                const int d = db * 16 + l16;
                Opart[(slab + q) * DH + d] = f2bf(o_acc[i][db][r]);
            }
        }
}

// ---------------------------------------------------------------------------
// Kernel 2b: merge split-K partials -> Ctx bf16 [s][E].
// One wave per (h,q) row; lane = d.
// ---------------------------------------------------------------------------
__global__ __launch_bounds__(256) void flash_merge(
    const short* __restrict__ Opart, const float* __restrict__ Mpart,
    const float* __restrict__ Lpart, short* __restrict__ Ctx)
{
    const int row = blockIdx.x * 4 + (threadIdx.x >> 6);
    const int lane = threadIdx.x & 63;
    const int h = row >> 12, q = row & 4095;
    const int nc = (q >> 10) + 1;

    float mv[NCHUNK], lv[NCHUNK];
    float M = NEG_BIG;
    #pragma unroll
    for (int c = 0; c < NCHUNK; c++) {
        if (c < nc) {
            mv[c] = Mpart[((size_t)h * NCHUNK + c) * S_LEN + q];
            lv[c] = Lpart[((size_t)h * NCHUNK + c) * S_LEN + q];
            M = fmaxf(M, mv[c]);
        }
    }
    float L = 0.f, O = 0.f;
    #pragma unroll
    for (int c = 0; c < NCHUNK; c++) {
        if (c < nc) {
            const float w = __expf(mv[c] - M);
            L += w * lv[c];
            O += w * bf2f(Opart[(((size_t)h * NCHUNK + c) * S_LEN + q) * DH + lane]);
        }
    }
    const float inv = (L > 0.f) ? 1.0f / L : 0.f;
    Ctx[(size_t)q * EMB + h * DH + lane] = f2bf(O * inv);
}

// ---------------------------------------------------------------------------
// Fallback single-pass flash (R3 version) in case ws_size is too small.
// ---------------------------------------------------------------------------
__global__ __launch_bounds__(256) void flash_attn(
    const short* __restrict__ Qw, const short* __restrict__ Kw,
    const short* __restrict__ Vt, short* __restrict__ Ctx)
{
    __shared__ __align__(16) short Ks[128 * 64];
    __shared__ __align__(16) short Vs[64 * 128];
    __shared__ __align__(16) short Ps[4][32 * 128];

    const int h  = blockIdx.y;
    const int qt = (gridDim.x - 1) - blockIdx.x;
    const int q0 = qt * 128;
    const int t = threadIdx.x;
    const int lane = t & 63, wave = t >> 6;
    const int quad = lane >> 4, l16 = lane & 15;
    const int qw0 = q0 + wave * 32;

    bf16x8 qf[2][2];
    #pragma unroll
    for (int i = 0; i < 2; i++)
        #pragma unroll
        for (int kb = 0; kb < 2; kb++)
            qf[i][kb] = *(const bf16x8*)
                &Qw[((size_t)h * S_LEN + qw0 + i * 16 + l16) * DH + kb * 32 + quad * 8];

    float m_i[2][4], l_i[2][4];
    f32x4 o_acc[2][4] = {};
    #pragma unroll
    for (int i = 0; i < 2; i++)
        #pragma unroll
        for (int r = 0; r < 4; r++) { m_i[i][r] = NEG_BIG; l_i[i][r] = 0.f; }

    for (int kt = 0; kt <= qt; kt++) {
        const int k0 = kt * 128;
        __syncthreads();
        for (int c = t; c < 1024; c += 256) {
            const int row = c >> 3, cc = (c & 7) * 8;
            *(bf16x8*)&Ks[row * 64 + cc] =
                *(const bf16x8*)&Kw[((size_t)h * S_LEN + k0 + row) * DH + cc];
        }
        for (int c = t; c < 1024; c += 256) {
            const int row = c >> 4, cc = (c & 15) * 8;
            *(bf16x8*)&Vs[row * 128 + cc] =
                *(const bf16x8*)&Vt[((size_t)h * DH + row) * S_LEN + k0 + cc];
        }
        __syncthreads();

        f32x4 sf[2][8] = {};
        #pragma unroll
        for (int j = 0; j < 8; j++) {
            #pragma unroll
            for (int kb = 0; kb < 2; kb++) {
                const bf16x8 kf = *(const bf16x8*)
                    &Ks[(j * 16 + l16) * 64 + kb * 32 + quad * 8];
                #pragma unroll
                for (int i = 0; i < 2; i++)
                    sf[i][j] = __builtin_amdgcn_mfma_f32_16x16x32_bf16(
                        qf[i][kb], kf, sf[i][j], 0, 0, 0);
            }
        }

        const bool diag = (kt == qt);
        #pragma unroll
        for (int i = 0; i < 2; i++) {
            if (diag) {
                const int qbase = qw0 + i * 16 + quad * 4;
                const int kbase = k0 + l16;
                #pragma unroll
                for (int j = 0; j < 8; j++)
                    #pragma unroll
                    for (int r = 0; r < 4; r++)
                        if (kbase + j * 16 > qbase + r) sf[i][j][r] = NEG_BIG;
            }
            #pragma unroll
            for (int r = 0; r < 4; r++) {
                float mx = sf[i][0][r];
                #pragma unroll
                for (int j = 1; j < 8; j++) mx = fmaxf(mx, sf[i][j][r]);
                #pragma unroll
                for (int off = 1; off < 16; off <<= 1)
                    mx = fmaxf(mx, __shfl_xor(mx, off, 64));
                const float mnew = fmaxf(m_i[i][r], mx);
                const float alpha = __expf(m_i[i][r] - mnew);
                m_i[i][r] = mnew;
                float rs = 0.f;
                #pragma unroll
                for (int j = 0; j < 8; j++) {
                    const float p = __expf(sf[i][j][r] - mnew);
                    sf[i][j][r] = p;
                    rs += p;
                }
                #pragma unroll
                for (int off = 1; off < 16; off <<= 1)
                    rs += __shfl_xor(rs, off, 64);
                l_i[i][r] = l_i[i][r] * alpha + rs;
                #pragma unroll
                for (int db = 0; db < 4; db++) o_acc[i][db][r] *= alpha;
            }
            #pragma unroll
            for (int j = 0; j < 8; j++)
                #pragma unroll
                for (int r = 0; r < 4; r++)
                    Ps[wave][(i * 16 + quad * 4 + r) * 128 + j * 16 + l16] =
                        f2bf(sf[i][j][r]);
        }

        #pragma unroll
        for (int kb = 0; kb < 4; kb++) {
            bf16x8 pf[2];
            #pragma unroll
            for (int i = 0; i < 2; i++)
                pf[i] = *(const bf16x8*)
                    &Ps[wave][(i * 16 + l16) * 128 + kb * 32 + quad * 8];
            #pragma unroll
            for (int db = 0; db < 4; db++) {
                const bf16x8 vf = *(const bf16x8*)
                    &Vs[(db * 16 + l16) * 128 + kb * 32 + quad * 8];
                #pragma unroll
                for (int i = 0; i < 2; i++)
                    o_acc[i][db] = __builtin_amdgcn_mfma_f32_16x16x32_bf16(
                        pf[i], vf, o_acc[i][db], 0, 0, 0);
            }
        }
    }

    #pragma unroll
    for (int i = 0; i < 2; i++)
        #pragma unroll
        for (int r = 0; r < 4; r++) {
            const float li = l_i[i][r];
            const float inv = (li > 0.f) ? 1.0f / li : 0.f;
            const int m = qw0 + i * 16 + quad * 4 + r;
            #pragma unroll
            for (int db = 0; db < 4; db++) {
                const int d = db * 16 + l16;
                Ctx[(size_t)m * EMB + h * DH + d] = f2bf(o_acc[i][db][r] * inv);
            }
        }
}

// ---------------------------------------------------------------------------
// Kernel 3: output projection (unchanged from R3, passing).
// ---------------------------------------------------------------------------
__global__ __launch_bounds__(256) void out_gemm(
    const short* __restrict__ A, const float* __restrict__ W,
    const float* __restrict__ Bias, float* __restrict__ Out)
{
    __shared__ __align__(16) short As[128 * 32];
    __shared__ __align__(16) short Bs[128 * 32];

    const int m0 = blockIdx.x * 128;
    const int n0 = blockIdx.y * 128;
    const int t = threadIdx.x;
    const int lane = t & 63, wave = t >> 6;
    const int quad = lane >> 4, l16 = lane & 15;
    const int wm = (wave >> 1) * 64, wn = (wave & 1) * 64;

    f32x4 acc[4][4] = {};

    for (int k0 = 0; k0 < EMB; k0 += 32) {
        __syncthreads();
        for (int c = t; c < 512; c += 256) {
            const int row = c >> 2, cc = (c & 3) * 8;
            *(bf16x8*)&As[row * 32 + cc] =
                *(const bf16x8*)&A[(size_t)(m0 + row) * EMB + k0 + cc];
        }
        for (int c = t; c < 1024; c += 256) {
            const int row = c >> 3, cc = (c & 7) * 4;
            const float4 vb = *(const float4*)&W[(size_t)(n0 + row) * EMB + k0 + cc];
            short4 sb; sb.x = f2bf(vb.x); sb.y = f2bf(vb.y);
                       sb.z = f2bf(vb.z); sb.w = f2bf(vb.w);
            *(short4*)&Bs[row * 32 + cc] = sb;
        }
        __syncthreads();

        bf16x8 af[4], bfr[4];
        #pragma unroll
        for (int i = 0; i < 4; i++)
            af[i] = *(const bf16x8*)&As[(wm + i * 16 + l16) * 32 + quad * 8];
        #pragma unroll
        for (int j = 0; j < 4; j++)
            bfr[j] = *(const bf16x8*)&Bs[(wn + j * 16 + l16) * 32 + quad * 8];
        #pragma unroll
        for (int i = 0; i < 4; i++)
            #pragma unroll
            for (int j = 0; j < 4; j++)
                acc[i][j] = __builtin_amdgcn_mfma_f32_16x16x32_bf16(
                    af[i], bfr[j], acc[i][j], 0, 0, 0);
    }

    #pragma unroll
    for (int j = 0; j < 4; j++) {
        const int n = n0 + wn + j * 16 + l16;
        const float bias = Bias[n];
        #pragma unroll
        for (int i = 0; i < 4; i++)
            #pragma unroll
            for (int r = 0; r < 4; r++) {
                const int m = m0 + wm + i * 16 + quad * 4 + r;
                Out[(size_t)m * EMB + n] = acc[i][j][r] + bias;
            }
    }
}

// ---------------------------------------------------------------------------
extern "C" void kernel_launch(void* const* d_in, const int* in_sizes, int n_in,
                              void* d_out, int out_size, void* d_ws, size_t ws_size,
                              hipStream_t stream)
{
    (void)in_sizes; (void)n_in; (void)out_size;
    const float* x     = (const float*)d_in[0];
    const float* w_qkv = (const float*)d_in[2];
    const float* b_qkv = (const float*)d_in[3];
    const float* w_out = (const float*)d_in[4];
    const float* b_out = (const float*)d_in[5];
    float* out = (float*)d_out;

    char* ws = (char*)d_ws;
    const size_t SEG = (size_t)NH * S_LEN * DH * sizeof(short);     // 6 MB
    short* Qw  = (short*)(ws);
    short* Kw  = (short*)(ws + SEG);
    short* Vt  = (short*)(ws + 2 * SEG);
    short* Ctx = (short*)(ws + 3 * SEG);
    // split-K partial buffers
    const size_t OP_OFF = 4 * SEG;
    const size_t OP_SZ  = (size_t)NH * NCHUNK * S_LEN * DH * sizeof(short); // 25.2 MB
    const size_t ML_SZ  = (size_t)NH * NCHUNK * S_LEN * sizeof(float);      // 0.79 MB
    short* Opart = (short*)(ws + OP_OFF);
    float* Mpart = (float*)(ws + OP_OFF + OP_SZ);
    float* Lpart = (float*)(ws + OP_OFF + OP_SZ + ML_SZ);
    const size_t need = OP_OFF + OP_SZ + 2 * ML_SZ;

    qkv_gemm<<<dim3(S_LEN / 128, (3 * EMB) / 128), 256, 0, stream>>>(
        x, w_qkv, b_qkv, Qw, Kw, Vt);

    if (ws_size >= need) {
        flash_partial<<<dim3(S_LEN / 128, NH, NCHUNK), 256, 0, stream>>>(
            Qw, Kw, Vt, Opart, Mpart, Lpart);
        flash_merge<<<dim3(NH * S_LEN / 4), 256, 0, stream>>>(
            Opart, Mpart, Lpart, Ctx);
    } else {
        flash_attn<<<dim3(S_LEN / 128, NH), 256, 0, stream>>>(Qw, Kw, Vt, Ctx);
    }

    out_gemm<<<dim3(S_LEN / 128, EMB / 128), 256, 0, stream>>>(
        Ctx, w_out, b_out, out);
}